// Round 2
// baseline (100.240 us; speedup 1.0000x reference)
//
#include <hip/hip_runtime.h>
#include <cstddef>

namespace {

constexpr int B  = 32;
constexpr int NB = 688;
constexpr int K  = 4;
constexpr int L  = 688;
constexpr int S  = 688;
constexpr int V  = 50;
constexpr int LS = L + S;            // 1376
constexpr int ROWS  = B * NB;        // 22016 pointer / contrastive rows
constexpr int TROWS = B * S;         // 22016 tag rows
constexpr float TINV = 10.0f;        // 1 / TEMP
constexpr int Q  = S / 4;            // 172 float4 per row
constexpr int Q3 = Q - 128;          // 44: lanes with a valid 3rd quad

// role block counts (proportional to HBM bytes per role)
constexpr int NPTR = 680, NROW = 1320, NCOL = 1320, NTAG = 128, NEMP = 8;
constexpr int NBLK = NPTR + NROW + NCOL + NTAG + NEMP;   // 3456

// ws layout (doubles)
constexpr int PT0 = 0;               // ptr total        [680]
constexpr int PH0 = 680;             // ptr has-count    [680]
constexpr int RS0 = 1360;            // row sum          [1320]
constexpr int RV0 = 2680;            // row vb-count     [1320]
constexpr int CS0 = 4000;            // col sum          [1320]
constexpr int CV0 = 5320;            // col vb-count     [1320]
constexpr int TS0 = 6640;            // tag sum          [128]
constexpr int TC0 = 6768;            // tag valid count  [128]
constexpr int ES0 = 6896;            // empty partial    [8]

__device__ __forceinline__ float wred_max(float v) {
#pragma unroll
  for (int o = 32; o > 0; o >>= 1) v = fmaxf(v, __shfl_xor(v, o));
  return v;
}
__device__ __forceinline__ float wred_sum(float v) {
#pragma unroll
  for (int o = 32; o > 0; o >>= 1) v += __shfl_xor(v, o);
  return v;
}

__device__ __forceinline__ float q_max(const float4& a) {
  return fmaxf(fmaxf(a.x, a.y), fmaxf(a.z, a.w));
}
__device__ __forceinline__ float q_expsum(const float4& a, float m) {
  return __expf(a.x - m) + __expf(a.y - m) + __expf(a.z - m) + __expf(a.w - m);
}
__device__ __forceinline__ float4 q_scale(float4 a) {
  a.x *= TINV; a.y *= TINV; a.z *= TINV; a.w *= TINV; return a;
}

// one (x, coef) component of the contrastive inner sum
__device__ __forceinline__ void c_comp(float xs, float c, float m, float zinv,
                                       float& wsum, float& csum, float& anyv) {
  float p  = __expf(xs - m) * zinv;
  float lp = __logf(p + 1e-8f);          // matches log(softmax + 1e-8)
  csum += c;
  if (c >= 0.f) { wsum += c * lp; anyv = 1.f; }
}
__device__ __forceinline__ void c_quad(const float4& x, const float4& c,
                                       float m, float zinv,
                                       float& wsum, float& csum, float& anyv) {
  c_comp(x.x, c.x, m, zinv, wsum, csum, anyv);
  c_comp(x.y, c.y, m, zinv, wsum, csum, anyv);
  c_comp(x.z, c.z, m, zinv, wsum, csum, anyv);
  c_comp(x.w, c.w, m, zinv, wsum, csum, anyv);
}

// ---------------- pointer loss row: (b, nb) ----------------
__device__ __forceinline__ void ptr_row(int r, int lane,
    const float* __restrict__ plog, const int* __restrict__ box,
    const int* __restrict__ dmask, double& a0, double& a1)
{
  const float*  pl  = plog + (size_t)r * S;
  const float4* pl4 = reinterpret_cast<const float4*>(pl);
  const bool t3 = (lane < Q3);
  float4 x0 = q_scale(pl4[lane]);
  float4 x1 = q_scale(pl4[lane + 64]);
  float4 x2 = t3 ? q_scale(pl4[lane + 128])
                 : make_float4(-INFINITY, -INFINITY, -INFINITY, -INFINITY);
  float m = fmaxf(q_max(x0), fmaxf(q_max(x1), q_max(x2)));
  m = wred_max(m);
  float z = q_expsum(x0, m) + q_expsum(x1, m) + q_expsum(x2, m); // exp(-inf)=0
  z = wred_sum(z);
  float lse = m + __logf(z);

  float g = 0.f, vld = 0.f;
  if (lane < K) {
    int idx = box[(size_t)r * K + lane];
    if (idx != -1) {
      vld = 1.f;
      int b  = r / NB;
      int vp = dmask[(size_t)b * LS + L + idx];
      float sv = pl[idx] * TINV;               // L1-resident (row just read)
      g = vp ? (sv - lse) : -INFINITY;
    }
  }
  float gs  = wred_sum(g);
  float cnt = wred_sum(vld);
  if (cnt > 0.f) {
    a0 += (double)(-(gs / fmaxf(cnt, 1.f)));
    a1 += 1.0;
  }
}

// ---------------- contrastive loss row ----------------
__device__ __forceinline__ void con_row(int r, int lane,
    const float* __restrict__ sim, const float* __restrict__ coef,
    double& a0, double& a1)
{
  const float4* sp4 = reinterpret_cast<const float4*>(sim  + (size_t)r * S);
  const float4* cp4 = reinterpret_cast<const float4*>(coef + (size_t)r * S);
  const bool t3 = (lane < Q3);
  float4 x0 = q_scale(sp4[lane]);
  float4 x1 = q_scale(sp4[lane + 64]);
  float4 x2 = t3 ? q_scale(sp4[lane + 128])
                 : make_float4(-INFINITY, -INFINITY, -INFINITY, -INFINITY);
  float m = fmaxf(q_max(x0), fmaxf(q_max(x1), q_max(x2)));
  m = wred_max(m);
  float z = q_expsum(x0, m) + q_expsum(x1, m) + q_expsum(x2, m);
  z = wred_sum(z);
  float zinv = 1.0f / z;

  float wsum = 0.f, csum = 0.f, anyv = 0.f;
  {
    float4 c0 = cp4[lane];
    c_quad(x0, c0, m, zinv, wsum, csum, anyv);
  }
  {
    float4 c1 = cp4[lane + 64];
    c_quad(x1, c1, m, zinv, wsum, csum, anyv);
  }
  if (t3) {
    float4 c2 = cp4[lane + 128];
    c_quad(x2, c2, m, zinv, wsum, csum, anyv);
  }
  wsum = wred_sum(wsum); csum = wred_sum(csum); anyv = wred_sum(anyv);
  if (anyv > 0.f) {
    a0 += (double)(-(wsum / (csum + 1e-8f)));
    a1 += 1.0;
  }
}

// ---------------- tag loss row ----------------
__device__ __forceinline__ void tag_row(int row, int lane,
    const float* __restrict__ tl_base, const int* __restrict__ tgt,
    double& a0, double& a1)
{
  const float* tl = tl_base + (size_t)row * V;
  float xv = (lane < V) ? tl[lane] : -INFINITY;
  float m  = wred_max(xv);
  float ev = (lane < V) ? __expf(xv - m) : 0.f;
  float z  = wred_sum(ev);
  float sx = (lane < V) ? xv : 0.f;
  float sumx = wred_sum(sx);
  float lse = m + __logf(z);
  int t = tgt[row];
  float xt = __shfl(xv, t);          // t in [0, 50)
  if (t != 0) {                      // PAD == 0
    // per = 0.9*(lse - x_t) + 0.1*(lse - mean_x)
    a0 += (double)(lse - 0.9f * xt - 0.1f * (sumx * (1.0f / (float)V)));
    a1 += 1.0;
  }
}

// ---------------- empty BCE row (one batch b per wave) ----------------
__device__ __forceinline__ void empty_row(int b, int lane,
    const float* __restrict__ elog, const int* __restrict__ dmask,
    const int* __restrict__ emask, double& a0)
{
  const float* el = elog + (size_t)b * S;
  const int* dm = dmask + (size_t)b * LS + L;
  const int* em = emask + (size_t)b * LS + L;
  float bs = 0.f, bc = 0.f;
  for (int j = lane; j < S; j += 64) {
    float xv = el[j];
    int d = dm[j], e = em[j];
    float tt = (float)e;
    float bce = fmaxf(xv, 0.f) - xv * tt + log1pf(__expf(-fabsf(xv)));
    if (d | e) { bs += bce; bc += 1.f; }
  }
  bs = wred_sum(bs);
  bc = wred_sum(bc);
  a0 += (double)(bs / (bc + 1e-8f));
}

__global__ __launch_bounds__(256) void fused_loss(
    const float* __restrict__ tag_logits, const int* __restrict__ tag_targets,
    const float* __restrict__ plog, const int* __restrict__ box,
    const int* __restrict__ dmask, const int* __restrict__ emask,
    const float* __restrict__ elog,
    const float* __restrict__ rsim, const float* __restrict__ csim,
    const float* __restrict__ rcoef, const float* __restrict__ ccoef,
    double* __restrict__ ws)
{
  const int tid  = threadIdx.x;
  const int lane = tid & 63;
  const int wave = tid >> 6;
  const int bid  = blockIdx.x;

  double a0 = 0.0, a1 = 0.0;
  int role, rb;
  if      (bid < NPTR)                      { role = 0; rb = bid; }
  else if (bid < NPTR + NROW)               { role = 1; rb = bid - NPTR; }
  else if (bid < NPTR + NROW + NCOL)        { role = 2; rb = bid - (NPTR + NROW); }
  else if (bid < NPTR + NROW + NCOL + NTAG) { role = 3; rb = bid - (NPTR + NROW + NCOL); }
  else                                      { role = 4; rb = bid - (NPTR + NROW + NCOL + NTAG); }

  if (role == 0) {
    const int wid = rb * 4 + wave, W = NPTR * 4;
    for (int r = wid; r < ROWS; r += W) ptr_row(r, lane, plog, box, dmask, a0, a1);
  } else if (role == 1) {
    const int wid = rb * 4 + wave, W = NROW * 4;
    for (int r = wid; r < ROWS; r += W) con_row(r, lane, rsim, rcoef, a0, a1);
  } else if (role == 2) {
    const int wid = rb * 4 + wave, W = NCOL * 4;
    for (int r = wid; r < ROWS; r += W) con_row(r, lane, csim, ccoef, a0, a1);
  } else if (role == 3) {
    const int wid = rb * 4 + wave, W = NTAG * 4;
    for (int r = wid; r < TROWS; r += W) tag_row(r, lane, tag_logits, tag_targets, a0, a1);
  } else {
    const int b = rb * 4 + wave;   // 8 blocks * 4 waves = 32 batches
    empty_row(b, lane, elog, dmask, emask, a0);
  }

  __shared__ double s0[4], s1[4];
  if (lane == 0) { s0[wave] = a0; s1[wave] = a1; }
  __syncthreads();
  if (tid == 0) {
    double t0 = s0[0] + s0[1] + s0[2] + s0[3];
    double t1 = s1[0] + s1[1] + s1[2] + s1[3];
    switch (role) {
      case 0:  ws[PT0 + rb] = t0; ws[PH0 + rb] = t1; break;
      case 1:  ws[RS0 + rb] = t0; ws[RV0 + rb] = t1; break;
      case 2:  ws[CS0 + rb] = t0; ws[CV0 + rb] = t1; break;
      case 3:  ws[TS0 + rb] = t0; ws[TC0 + rb] = t1; break;
      default: ws[ES0 + rb] = t0; break;
    }
  }
}

__global__ void combine_kernel(const double* __restrict__ ws,
                               float* __restrict__ out)
{
  const int lane = threadIdx.x;   // blockDim.x == 64
  double pt = 0, ph = 0, rs = 0, rv = 0, cs = 0, cv = 0, ts = 0, tc = 0, es = 0;
  for (int i = lane; i < NROW; i += 64) {
    rs += ws[RS0 + i]; rv += ws[RV0 + i];
    cs += ws[CS0 + i]; cv += ws[CV0 + i];
  }
  for (int i = lane; i < NPTR; i += 64) { pt += ws[PT0 + i]; ph += ws[PH0 + i]; }
  for (int i = lane; i < NTAG; i += 64) { ts += ws[TS0 + i]; tc += ws[TC0 + i]; }
  if (lane < NEMP) es = ws[ES0 + lane];
#pragma unroll
  for (int o = 32; o > 0; o >>= 1) {
    pt += __shfl_xor(pt, o); ph += __shfl_xor(ph, o);
    rs += __shfl_xor(rs, o); rv += __shfl_xor(rv, o);
    cs += __shfl_xor(cs, o); cv += __shfl_xor(cv, o);
    ts += __shfl_xor(ts, o); tc += __shfl_xor(tc, o);
    es += __shfl_xor(es, o);
  }
  if (lane == 0) {
    float cls  = (float)(ts / tc);
    float ptr  = (float)(pt / (ph + 1e-6));
    float emp  = (float)(es / (double)B);
    float row  = (float)(rs / (rv + 1e-8));
    float col  = (float)(cs / (cv + 1e-8));
    float total = cls + ptr + emp + 0.5f * row + 0.5f * col;
    out[0] = total; out[1] = cls; out[2] = ptr;
    out[3] = emp;   out[4] = row; out[5] = col;
  }
}

} // anonymous namespace

extern "C" void kernel_launch(void* const* d_in, const int* in_sizes, int n_in,
                              void* d_out, int out_size, void* d_ws, size_t ws_size,
                              hipStream_t stream)
{
  const float* tag_logits  = (const float*)d_in[0];
  const int*   tag_targets = (const int*)  d_in[1];
  const float* plog        = (const float*)d_in[2];
  const int*   box         = (const int*)  d_in[3];
  const int*   dmask       = (const int*)  d_in[4];
  const int*   emask       = (const int*)  d_in[5];
  const float* elog        = (const float*)d_in[6];
  const float* rsim        = (const float*)d_in[7];
  const float* csim        = (const float*)d_in[8];
  const float* rcoef       = (const float*)d_in[9];
  const float* ccoef       = (const float*)d_in[10];

  double* ws = (double*)d_ws;
  float* out = (float*)d_out;

  fused_loss<<<NBLK, 256, 0, stream>>>(tag_logits, tag_targets, plog, box,
                                       dmask, emask, elog, rsim, csim,
                                       rcoef, ccoef, ws);
  combine_kernel<<<1, 64, 0, stream>>>(ws, out);
}

// Round 3
// 71.316 us; speedup vs baseline: 1.4056x; 1.4056x over previous
//
#include <hip/hip_runtime.h>
#include <cstddef>

namespace {

constexpr int B  = 32;
constexpr int NB = 688;
constexpr int K  = 4;
constexpr int L  = 688;
constexpr int S  = 688;
constexpr int V  = 50;
constexpr int LS = L + S;            // 1376
constexpr int ROWS  = B * NB;        // 22016 (same count for tag rows: B*S)
constexpr float TINV = 10.0f;        // 1 / TEMP
constexpr int Q3 = S / 4 - 128;      // 44: lanes with a valid 3rd quad

constexpr int NBLK = 2048;           // 8 blocks/CU exactly; uniform work

// ws: 9 float arrays of [NBLK]
constexpr int A_PT = 0, A_PH = 1, A_RS = 2, A_RV = 3, A_CS = 4,
              A_CV = 5, A_TS = 6, A_TC = 7, A_ES = 8;

__device__ __forceinline__ float wred_sum(float v) {
#pragma unroll
  for (int o = 32; o > 0; o >>= 1) v += __shfl_xor(v, o);
  return v;
}

__device__ __forceinline__ float4 q_exp_t(const float4 v) {
  return make_float4(__expf(v.x * TINV), __expf(v.y * TINV),
                     __expf(v.z * TINV), __expf(v.w * TINV));
}
__device__ __forceinline__ float q_sum(const float4 a) {
  return (a.x + a.y) + (a.z + a.w);
}

// pass-2 quad for contrastive: csum += c; if c>=0: wsum += c*(log(e+A)-lgz)
__device__ __forceinline__ void c_quad(const float4 e, const float4 c,
                                       float A, float lgz,
                                       float& wsum, float& csum, bool& anyv) {
  csum += ((c.x + c.y) + (c.z + c.w));
  if (c.x >= 0.f) { wsum += c.x * (__logf(e.x + A) - lgz); anyv = true; }
  if (c.y >= 0.f) { wsum += c.y * (__logf(e.y + A) - lgz); anyv = true; }
  if (c.z >= 0.f) { wsum += c.z * (__logf(e.z + A) - lgz); anyv = true; }
  if (c.w >= 0.f) { wsum += c.w * (__logf(e.w + A) - lgz); anyv = true; }
}

// ---------------- contrastive loss row ----------------
__device__ __forceinline__ void con_row(int r, int lane,
    const float* __restrict__ sim, const float* __restrict__ coef,
    float& a0, float& a1)
{
  const float4* sp4 = reinterpret_cast<const float4*>(sim  + (size_t)r * S);
  const float4* cp4 = reinterpret_cast<const float4*>(coef + (size_t)r * S);
  const bool t3 = (lane < Q3);
  // all loads issued up-front (memory-level parallelism)
  float4 v0 = sp4[lane];
  float4 v1 = sp4[lane + 64];
  float4 c0 = cp4[lane];
  float4 c1 = cp4[lane + 64];
  float4 v2 = t3 ? sp4[lane + 128] : make_float4(0, 0, 0, 0);
  float4 c2 = t3 ? cp4[lane + 128] : make_float4(0, 0, 0, 0);

  float4 e0 = q_exp_t(v0);
  float4 e1 = q_exp_t(v1);
  float4 e2 = t3 ? q_exp_t(v2) : make_float4(0, 0, 0, 0);

  float z = q_sum(e0) + q_sum(e1) + q_sum(e2);
  z = wred_sum(z);                       // 6-deep DS chain (no max pass)
  float A   = 1e-8f * z;                 // log(e/z + 1e-8) = log(e + A) - log z
  float lgz = __logf(z);

  float wsum = 0.f, csum = 0.f;
  bool  anyv = false;
  c_quad(e0, c0, A, lgz, wsum, csum, anyv);
  c_quad(e1, c1, A, lgz, wsum, csum, anyv);
  if (t3) c_quad(e2, c2, A, lgz, wsum, csum, anyv);

  wsum = wred_sum(wsum);                 // two parallel 6-deep chains
  csum = wred_sum(csum);
  if (__ballot(anyv)) {                  // scalar, no DS chain
    a0 += -(wsum / (csum + 1e-8f));
    a1 += 1.f;
  }
}

// ---------------- pointer loss row ----------------
__device__ __forceinline__ void ptr_row(int r, int lane,
    const float* __restrict__ plog, const int* __restrict__ box,
    const int* __restrict__ dmask, float& a0, float& a1)
{
  const float*  pl  = plog + (size_t)r * S;
  const float4* pl4 = reinterpret_cast<const float4*>(pl);
  const bool t3 = (lane < Q3);
  float4 v0 = pl4[lane];
  float4 v1 = pl4[lane + 64];
  float4 v2 = t3 ? pl4[lane + 128] : make_float4(0, 0, 0, 0);
  int idx = (lane < K) ? box[(size_t)r * K + lane] : -1;

  float4 e0 = q_exp_t(v0);
  float4 e1 = q_exp_t(v1);
  float4 e2 = t3 ? q_exp_t(v2) : make_float4(0, 0, 0, 0);
  float z = q_sum(e0) + q_sum(e1) + q_sum(e2);
  z = wred_sum(z);
  float lse = __logf(z);

  bool vld = (idx != -1) & (lane < K);
  float g = 0.f;
  if (vld) {
    int bb = r / NB;
    int vp = dmask[(size_t)bb * LS + L + idx];
    float sv = pl[idx] * TINV;           // row is L1-resident
    g = vp ? (sv - lse) : -INFINITY;
  }
  g += __shfl_xor(g, 1);                 // 2-deep: sum over lanes 0..3
  g += __shfl_xor(g, 2);
  unsigned long long bal = __ballot(vld);
  int cnt = __popcll(bal);
  if (cnt > 0) {
    a0 += -(g / (float)cnt);             // only lane 0's a0 is consumed
    a1 += 1.f;
  }
}

// ---------------- tag loss row ----------------
__device__ __forceinline__ void tag_row(int row, int lane,
    const float* __restrict__ tl_base, const int* __restrict__ tgt,
    float& a0, float& a1)
{
  const float* tl = tl_base + (size_t)row * V;
  const bool a = (lane < V);
  float xv = a ? tl[lane] : 0.f;
  int   t  = tgt[row];                   // broadcast load
  float ev = a ? __expf(xv) : 0.f;
  float sx = a ? xv : 0.f;
  float z    = wred_sum(ev);             // two parallel chains
  float sumx = wred_sum(sx);
  float lse = __logf(z);
  float xt  = __shfl(xv, t);             // t in [0,50)
  if (t != 0) {                          // PAD == 0
    // (1-SM)*(lse-x_t) + SM*(lse - mean x) ; SM=0.1, mean = sumx/50
    a0 += lse - 0.9f * xt - 0.002f * sumx;
    a1 += 1.f;
  }
}

// ---------------- empty BCE (one batch per call) ----------------
__device__ __forceinline__ void empty_row(int b, int lane,
    const float* __restrict__ elog, const int* __restrict__ dmask,
    const int* __restrict__ emask, float& a0)
{
  const float* el = elog + (size_t)b * S;
  const int* dm = dmask + (size_t)b * LS + L;
  const int* em = emask + (size_t)b * LS + L;
  float bs = 0.f, bc = 0.f;
  for (int j = lane; j < S; j += 64) {
    float xv = el[j];
    int d = dm[j], e = em[j];
    float tt = (float)e;
    float bce = fmaxf(xv, 0.f) - xv * tt + log1pf(__expf(-fabsf(xv)));
    if (d | e) { bs += bce; bc += 1.f; }
  }
  bs = wred_sum(bs);
  bc = wred_sum(bc);
  a0 += bs / (bc + 1e-8f);
}

__global__ __launch_bounds__(256, 8) void fused_loss(
    const float* __restrict__ tag_logits, const int* __restrict__ tag_targets,
    const float* __restrict__ plog, const int* __restrict__ box,
    const int* __restrict__ dmask, const int* __restrict__ emask,
    const float* __restrict__ elog,
    const float* __restrict__ rsim, const float* __restrict__ csim,
    const float* __restrict__ rcoef, const float* __restrict__ ccoef,
    float* __restrict__ ws)
{
  const int tid  = threadIdx.x;
  const int lane = tid & 63;
  const int wave = tid >> 6;
  const int b    = blockIdx.x;

  // uniform slice of ALL row types: rows [(b*43)>>2, ((b+1)*43)>>2)
  const int start = (b * 43) >> 2;       // b * 22016 / 2048
  const int end   = ((b + 1) * 43) >> 2; // 10 or 11 rows per block

  float pt = 0.f, ph = 0.f, rs = 0.f, rv = 0.f, cs = 0.f, cv = 0.f,
        ts = 0.f, tc = 0.f, es = 0.f;

  for (int r = start + wave; r < end; r += 4) {
    con_row(r, lane, rsim, rcoef, rs, rv);   // two independent chains
    con_row(r, lane, csim, ccoef, cs, cv);   // back-to-back for ILP
  }
  for (int r = start + wave; r < end; r += 4) {
    ptr_row(r, lane, plog, box, dmask, pt, ph);
    tag_row(r, lane, tag_logits, tag_targets, ts, tc);
  }
  if (b < B && wave == (b & 3)) empty_row(b, lane, elog, dmask, emask, es);

  __shared__ float sacc[4][9];
  if (lane == 0) {
    sacc[wave][0] = pt; sacc[wave][1] = ph; sacc[wave][2] = rs;
    sacc[wave][3] = rv; sacc[wave][4] = cs; sacc[wave][5] = cv;
    sacc[wave][6] = ts; sacc[wave][7] = tc; sacc[wave][8] = es;
  }
  __syncthreads();
  if (tid < 9) {
    float t0 = sacc[0][tid] + sacc[1][tid] + sacc[2][tid] + sacc[3][tid];
    ws[tid * NBLK + b] = t0;
  }
}

__global__ void combine_kernel(const float* __restrict__ ws,
                               float* __restrict__ out)
{
  const int lane = threadIdx.x;   // blockDim.x == 64
  double acc[9];
#pragma unroll
  for (int a = 0; a < 9; ++a) acc[a] = 0.0;
  for (int i = lane; i < NBLK; i += 64) {
#pragma unroll
    for (int a = 0; a < 9; ++a) acc[a] += (double)ws[a * NBLK + i];
  }
#pragma unroll
  for (int a = 0; a < 9; ++a) {
#pragma unroll
    for (int o = 32; o > 0; o >>= 1) acc[a] += __shfl_xor(acc[a], o);
  }
  if (lane == 0) {
    float cls  = (float)(acc[A_TS] / acc[A_TC]);
    float ptr  = (float)(acc[A_PT] / (acc[A_PH] + 1e-6));
    float emp  = (float)(acc[A_ES] / (double)B);
    float row  = (float)(acc[A_RS] / (acc[A_RV] + 1e-8));
    float col  = (float)(acc[A_CS] / (acc[A_CV] + 1e-8));
    float total = cls + ptr + emp + 0.5f * row + 0.5f * col;
    out[0] = total; out[1] = cls; out[2] = ptr;
    out[3] = emp;   out[4] = row; out[5] = col;
  }
}

} // anonymous namespace

extern "C" void kernel_launch(void* const* d_in, const int* in_sizes, int n_in,
                              void* d_out, int out_size, void* d_ws, size_t ws_size,
                              hipStream_t stream)
{
  const float* tag_logits  = (const float*)d_in[0];
  const int*   tag_targets = (const int*)  d_in[1];
  const float* plog        = (const float*)d_in[2];
  const int*   box         = (const int*)  d_in[3];
  const int*   dmask       = (const int*)  d_in[4];
  const int*   emask       = (const int*)  d_in[5];
  const float* elog        = (const float*)d_in[6];
  const float* rsim        = (const float*)d_in[7];
  const float* csim        = (const float*)d_in[8];
  const float* rcoef       = (const float*)d_in[9];
  const float* ccoef       = (const float*)d_in[10];

  float* ws  = (float*)d_ws;
  float* out = (float*)d_out;

  fused_loss<<<NBLK, 256, 0, stream>>>(tag_logits, tag_targets, plog, box,
                                       dmask, emask, elog, rsim, csim,
                                       rcoef, ccoef, ws);
  combine_kernel<<<1, 64, 0, stream>>>(ws, out);
}